// Round 6
// baseline (213.442 us; speedup 1.0000x reference)
//
#include <hip/hip_runtime.h>

typedef __attribute__((ext_vector_type(8))) short short8;   // 8 bf16 (4 VGPRs) MFMA A/B frag
typedef __attribute__((ext_vector_type(4))) float f32x4;    // MFMA C/D frag

constexpr int B_ROWS   = 524288;
constexpr int ROWTILES = B_ROWS / 64;   // 8192 tiles of 64 rows
constexpr int GRID     = 1024;          // 4 blocks/CU, all co-resident
constexpr int ITERS    = ROWTILES / GRID;   // 8 tiles per block
constexpr float L2E2   = 2.8853900817779268f;  // 2*log2(e)

union V16 { uint4 u; short8 s; };

// round-half-up bf16 pair pack: (bits+0x8000)>>16, two elems -> one u32 via v_perm.
__device__ __forceinline__ unsigned pk(float lo, float hi) {
  const unsigned a = __float_as_uint(lo) + 0x8000u;
  const unsigned b = __float_as_uint(hi) + 0x8000u;
  return __builtin_amdgcn_perm(b, a, 0x07060302u);  // dst = [a.hi16, b.hi16]
}

__device__ __forceinline__ V16 pk8(f32x4 a, f32x4 b) {
  V16 v;
  v.u.x = pk(a[0], a[1]); v.u.y = pk(a[2], a[3]);
  v.u.z = pk(b[0], b[1]); v.u.w = pk(b[2], b[3]);
  return v;
}

// acc[n,b] = L*b1[n] + sum_i (L*W1[n,i])*x[b,i]    (kb1 as MFMA acc init)
// P = sum_h w2m / (1+exp2(acc)), paired: (wa*tb+wb*ta)*rcp(ta*tb), t=1+E  [exact]
// out[b,k] = 1 - 1/(exp2(L*P + KS[k])+1); cross-quad reduce: shfl16 + LDS half-sums,
// final sigmoid distributed over all 256 threads in the store phase.
__global__ __launch_bounds__(256, 4) void fused_mlp8(
    const float* __restrict__ x, const float* __restrict__ W1,
    const float* __restrict__ b1, const float* __restrict__ W2,
    const float* __restrict__ b2, float* __restrict__ out) {

  __shared__ V16  xb[2][512];        // 2 x 64 rows x 8 chunks(16B), xor-swizzled
  __shared__ float ob[2][64 * 18];   // 2 x (64 rows x [halfA k0..7 | halfB k0..7] pad 2)
  __shared__ float kshare[8];

  const int tid  = threadIdx.x;
  const int wave = tid >> 6;
  const int lane = tid & 63;
  const int m16  = lane & 15;
  const int q    = lane >> 4;

  // ---- W1 A-fragments (scaled by L2E2): lane holds rows n=(4w+mt)*16+m16
  short8 w1f[4][2];
#pragma unroll
  for (int mt = 0; mt < 4; ++mt) {
    const int n = (wave * 4 + mt) * 16 + m16;
#pragma unroll
    for (int ks = 0; ks < 2; ++ks) {
      const float* p = W1 + n * 64 + ks * 32 + q * 8;
      const f32x4 u0 = *(const f32x4*)p, u1 = *(const f32x4*)(p + 4);
      f32x4 s0, s1;
#pragma unroll
      for (int r = 0; r < 4; ++r) { s0[r] = L2E2 * u0[r]; s1[r] = L2E2 * u1[r]; }
      w1f[mt][ks] = pk8(s0, s1).s;
    }
  }

  // ---- per-lane constants for C-layout rows n0 = (4w+mt)*16 + 4q
  f32x4 kb1[4], w2m[4];
  float sw2[2] = {0.f, 0.f};
#pragma unroll
  for (int mt = 0; mt < 4; ++mt) {
    const int n0 = (wave * 4 + mt) * 16 + q * 4;
    const f32x4 b1x = *(const f32x4*)(b1 + n0);
    const f32x4 w2x = *(const f32x4*)(W2 + n0);
#pragma unroll
    for (int r = 0; r < 4; ++r) {
      kb1[mt][r] = L2E2 * b1x[r];
      w2m[mt][r] = -2.0f * w2x[r];
      sw2[mt >> 1] += w2x[r];
    }
  }
#pragma unroll
  for (int j = 0; j < 2; ++j) {       // KS[k] = L*(sum_h w2 + b2), shared to all
    float s = sw2[j];
    s += __shfl_xor(s, 16);
    s += __shfl_xor(s, 32);
    if (lane == 0) kshare[wave * 2 + j] = L2E2 * (s + b2[wave * 2 + j]);
  }

  // ---- staging geometry: thread covers row=tid>>2, cols seg*16..+15 (64B)
  const int srow = tid >> 2;
  const int seg  = tid & 3;
  const int sw   = srow & 7;
  const float* gbase = x + (long)srow * 64 + seg * 16;
  const int orow = tid >> 2, oc = (tid & 3) * 2;   // store-phase mapping

  // ---- prologue: tile0 -> xb[0]; tile1 -> regs
  f32x4 pf[4];
#pragma unroll
  for (int c = 0; c < 4; ++c)
    pf[c] = *(const f32x4*)(gbase + (long)blockIdx.x * 4096 + c * 4);
  xb[0][srow * 8 + ((seg * 2)     ^ sw)] = pk8(pf[0], pf[1]);
  xb[0][srow * 8 + ((seg * 2 + 1) ^ sw)] = pk8(pf[2], pf[3]);
#pragma unroll
  for (int c = 0; c < 4; ++c)
    pf[c] = *(const f32x4*)(gbase + ((long)blockIdx.x + GRID) * 4096 + c * 4);
  __syncthreads();

  const float KS0 = kshare[oc], KS1 = kshare[oc + 1];

#pragma unroll
  for (int i = 0; i < ITERS; ++i) {
    const int p = i & 1;
    const long tile = (long)blockIdx.x + (long)i * GRID;

    // ---- compute tile i from xb[p] -> ob[p]
#pragma unroll
    for (int tt = 0; tt < 4; ++tt) {
      const int r   = tt * 16 + m16;
      const int rsw = r & 7;
      const short8 xf0 = xb[p][r * 8 + (q       ^ rsw)].s;
      const short8 xf1 = xb[p][r * 8 + ((q + 4) ^ rsw)].s;

      f32x4 acc[4];
#pragma unroll
      for (int mt = 0; mt < 4; ++mt) {
        f32x4 z = kb1[mt];                       // b1 folded into acc init
        z = __builtin_amdgcn_mfma_f32_16x16x32_bf16(w1f[mt][0], xf0, z, 0, 0, 0);
        z = __builtin_amdgcn_mfma_f32_16x16x32_bf16(w1f[mt][1], xf1, z, 0, 0, 0);
        acc[mt] = z;
      }

      float P0 = 0.f, P1 = 0.f;
#pragma unroll
      for (int j = 0; j < 2; ++j) {
        float P = 0.f;
#pragma unroll
        for (int t = 0; t < 2; ++t) {
          const int mt = j * 2 + t;
#pragma unroll
          for (int pr = 0; pr < 2; ++pr) {       // paired sigmoid: one rcp per 2 units
            const float ta = 1.0f + __builtin_amdgcn_exp2f(acc[mt][pr * 2]);
            const float tb = 1.0f + __builtin_amdgcn_exp2f(acc[mt][pr * 2 + 1]);
            const float N  = __builtin_fmaf(w2m[mt][pr * 2], tb,
                                            w2m[mt][pr * 2 + 1] * ta);
            P = __builtin_fmaf(N, __builtin_amdgcn_rcpf(ta * tb), P);
          }
        }
        P += __shfl_xor(P, 16);                  // q0+q1 / q2+q3 half-sums
        if (j == 0) P0 = P; else P1 = P;
      }
      if (q == 0) {                              // halfA: rows' k-pair for this wave
        float2 st; st.x = P0; st.y = P1;
        *(float2*)&ob[p][r * 18 + wave * 2] = st;
      }
      if (q == 2) {                              // halfB at +8 floats
        float2 st; st.x = P0; st.y = P1;
        *(float2*)&ob[p][r * 18 + 8 + wave * 2] = st;
      }
    }

    // ---- pack tile i+1 regs -> xb[p^1] (overlaps compute; pre-barrier)
    if (i + 1 < ITERS) {
      xb[p ^ 1][srow * 8 + ((seg * 2)     ^ sw)] = pk8(pf[0], pf[1]);
      xb[p ^ 1][srow * 8 + ((seg * 2 + 1) ^ sw)] = pk8(pf[2], pf[3]);
    }

    __syncthreads();   // the ONLY barrier per iteration

    // ---- store phase: cross-half add + final sigmoid spread over all 256 threads
    {
      const float2 ha = *(const float2*)&ob[p][orow * 18 + oc];
      const float2 hb = *(const float2*)&ob[p][orow * 18 + 8 + oc];
      const float a0 = __builtin_fmaf(ha.x + hb.x, L2E2, KS0);
      const float a1 = __builtin_fmaf(ha.y + hb.y, L2E2, KS1);
      float2 o;
      o.x = 1.0f - __builtin_amdgcn_rcpf(__builtin_amdgcn_exp2f(a0) + 1.0f);
      o.y = 1.0f - __builtin_amdgcn_rcpf(__builtin_amdgcn_exp2f(a1) + 1.0f);
      *(float2*)(out + (tile * 64 + orow) * 8 + oc) = o;
    }

    // ---- issue tile i+2 loads; consumed at iteration i+1's pack
    if (i + 2 < ITERS) {
      const float* gp = gbase + (tile + 2 * GRID) * 4096;
#pragma unroll
      for (int c = 0; c < 4; ++c) pf[c] = *(const f32x4*)(gp + c * 4);
    }
  }
}

extern "C" void kernel_launch(void* const* d_in, const int* in_sizes, int n_in,
                              void* d_out, int out_size, void* d_ws, size_t ws_size,
                              hipStream_t stream) {
  const float* x  = (const float*)d_in[0];
  const float* W1 = (const float*)d_in[1];
  const float* b1 = (const float*)d_in[2];
  const float* W2 = (const float*)d_in[3];
  const float* b2 = (const float*)d_in[4];
  float* out = (float*)d_out;
  fused_mlp8<<<GRID, 256, 0, stream>>>(x, W1, b1, W2, b2, out);
}